// Round 1
// baseline (100.585 us; speedup 1.0000x reference)
//
#include <hip/hip_runtime.h>

// Problem constants
#define B_  2
#define L_  128
#define D_  256
#define H_  8
#define R_  4
#define DK_ 32
#define BL_ (B_*L_)
#define SXP 260   // padded row stride (floats) for LDS row arrays (bank decorrelation, 16B-aligned)

__device__ __forceinline__ float wredsum64(float v) {
    #pragma unroll
    for (int m = 32; m >= 1; m >>= 1) v += __shfl_xor(v, m, 64);
    return v;
}
__device__ __forceinline__ float wredmax64(float v) {
    #pragma unroll
    for (int m = 32; m >= 1; m >>= 1) v = fmaxf(v, __shfl_xor(v, m, 64));
    return v;
}

// K1: grid 1024 = 64 rowTiles(4 rows) x 16 cg(16 cols). LN on 4 rows, then 3 GEMVs
// for 16 cols x 4 rows — each weight line serves 4 rows. qk half-head partial
// dots -> qkpart[row][16]; pv -> ws. ALSO initializes out = q + fc_b (residual +
// bias) for this block's 4x16 slice, so K2 can atomically accumulate the fc GEMV
// (K3 is gone).
__global__ __launch_bounds__(256) void k_proj(
    const float* __restrict__ q, const float* __restrict__ k, const float* __restrict__ v,
    const float* __restrict__ Wq, const float* __restrict__ Wk, const float* __restrict__ Wv,
    const float* __restrict__ ln_g, const float* __restrict__ ln_b,
    const float* __restrict__ fc_b,
    float* __restrict__ pv, float* __restrict__ qkpart, float* __restrict__ dout)
{
    const int blk = blockIdx.x;
    const int rowTile = blk >> 4;
    const int cg = blk & 15;                 // 16 cols per block
    const int rbase = rowTile * 4;
    const int tid = threadIdx.x;

    __shared__ __align__(16) float sx[3][4 * SXP];   // qn,k,v x 4 rows (12.5 KB)
    __shared__ __align__(16) float partF[16 * 4 * 16]; // [kg][row][col16] (4 KB)
    __shared__ float spq[4][16], spk[4][16];

    // stage q,k,v: thread -> (r = tid>>6, f4c = tid&63), loop over the 3 tensors
    {
        const int r = tid >> 6, f4c = tid & 63;
        #pragma unroll
        for (int p = 0; p < 3; ++p) {
            const float* src = (p == 0 ? q : (p == 1 ? k : v)) + (size_t)(rbase + r) * D_;
            *reinterpret_cast<float4*>(&sx[p][r * SXP + f4c * 4]) =
                reinterpret_cast<const float4*>(src)[f4c];
        }
    }

    // init out = residual(q) + fc_b for this block's 4 rows x 16 cols (exactly-once
    // per element across the grid; K2's atomicAdds are stream-ordered after this).
    if (tid < 64) {
        const int rr = tid >> 4, cc = tid & 15;
        const int col = cg * 16 + cc;
        const size_t off = (size_t)(rbase + rr) * D_ + col;
        dout[off] = q[off] + fc_b[col];
    }
    __syncthreads();

    // LayerNorm: wave w owns row w; lane covers cols lane+64j. Shuffle-reduce
    // leaves the totals in every lane — no LDS broadcast needed.
    {
        const int r = tid >> 6, lane = tid & 63;
        float x0 = sx[0][r * SXP + lane];
        float x1 = sx[0][r * SXP + lane + 64];
        float x2 = sx[0][r * SXP + lane + 128];
        float x3 = sx[0][r * SXP + lane + 192];
        float s1 = x0 + x1 + x2 + x3;
        float s2 = x0*x0 + x1*x1 + x2*x2 + x3*x3;
        #pragma unroll
        for (int m = 32; m >= 1; m >>= 1) {
            s1 += __shfl_xor(s1, m, 64);
            s2 += __shfl_xor(s2, m, 64);
        }
        const float mu = s1 * (1.0f / D_);
        const float rs = rsqrtf(s2 * (1.0f / D_) - mu * mu + 1e-6f);
        sx[0][r * SXP + lane      ] = (x0 - mu) * rs * ln_g[lane      ] + ln_b[lane      ];
        sx[0][r * SXP + lane +  64] = (x1 - mu) * rs * ln_g[lane +  64] + ln_b[lane +  64];
        sx[0][r * SXP + lane + 128] = (x2 - mu) * rs * ln_g[lane + 128] + ln_b[lane + 128];
        sx[0][r * SXP + lane + 192] = (x3 - mu) * rs * ln_g[lane + 192] + ln_b[lane + 192];
    }
    __syncthreads();

    // GEMV: thread = (kg 0..15, row 0..3, c4 0..3); 16 K-steps; the 4 row-threads
    // of a (kg,c4) share every weight float4 (same address -> one line).
    const int kg  = tid >> 4;
    const int row = (tid >> 2) & 3;
    const int c4  = tid & 3;
    const int gc4 = cg * 4 + c4;             // global float4 col (0..63)
    const int kbase = kg * 16;

    #pragma unroll
    for (int m = 0; m < 3; ++m) {
        const float4* W4 = reinterpret_cast<const float4*>(m == 0 ? Wq : (m == 1 ? Wk : Wv));
        float4 a = {0, 0, 0, 0};
        #pragma unroll
        for (int kk = 0; kk < 16; ++kk) {
            const int kr = kbase + kk;
            const float x = sx[m][row * SXP + kr];
            const float4 w = W4[kr * 64 + gc4];
            a.x += x * w.x; a.y += x * w.y; a.z += x * w.z; a.w += x * w.w;
        }
        *reinterpret_cast<float4*>(&partF[(kg * 16 + row * 4 + c4) * 4]) = a;
        __syncthreads();
        if (tid < 64) {                      // reduce over kg: float idx kg*64 + rr*16 + cc
            const int rr = tid >> 4, cc = tid & 15;
            float sum = 0.f;
            #pragma unroll
            for (int g = 0; g < 16; ++g) sum += partF[g * 64 + rr * 16 + cc];
            if      (m == 0) spq[rr][cc] = sum;
            else if (m == 1) spk[rr][cc] = sum;
            else             pv[(size_t)(rbase + rr) * D_ + cg * 16 + cc] = sum;
        }
        __syncthreads();
    }

    // half-head partial dot: reduce spq*spk over the block's 16 cols
    if (tid < 64) {
        const int rr = tid >> 4, cc = tid & 15;
        float d = spq[rr][cc] * spk[rr][cc];
        #pragma unroll
        for (int m = 8; m >= 1; m >>= 1) d += __shfl_xor(d, m, 64);
        if (cc == 0) qkpart[(size_t)(rbase + rr) * 16 + cg] = d;
    }
}

// K2: grid 512 = b x 32 iTiles(4 i per block, one per wave) x 8 heads.
// Phi/Psi per (i_local,j), softmax per wave, mid with pv lines shared by 4 i's.
// NEW: the per-head mid slice (4 rows x 32 k) is folded through fc_w in-block and
// atomically accumulated into out (replaces the former k_fc kernel + mid tensor).
__global__ __launch_bounds__(256) void k_attn(
    const float* __restrict__ t, const float* __restrict__ omega, const float* __restrict__ s,
    const float* __restrict__ pv, const float* __restrict__ qkpart,
    const float* __restrict__ fc_w, float* __restrict__ dout)
{
    const int blk = blockIdx.x;
    const int b     = blk >> 8;
    const int itile = (blk >> 3) & 31;
    const int h     = blk & 7;
    const int ibase = itile * 4;
    const int tid = threadIdx.x;

    __shared__ __align__(16) float sQKp[L_ * 16];    // staged qk partials (8 KB)
    __shared__ __align__(16) float sQKh[L_];         // combined for this head
    __shared__ __align__(16) float sOm[4 * L_];
    __shared__ __align__(16) float sPhi[4 * L_], sPsi[4 * L_];
    __shared__ __align__(16) float sAttn[4 * L_];
    __shared__ __align__(16) float partF[32 * 4 * 32]; // [jg][w][col32] (16 KB)
    __shared__ float st[L_], sS[R_];
    __shared__ float sMid[4][32];                    // this head's mid slice

    // staging
    {
        const float4* qkp4 = reinterpret_cast<const float4*>(qkpart + (size_t)b * L_ * 16);
        reinterpret_cast<float4*>(sQKp)[tid]       = qkp4[tid];
        reinterpret_cast<float4*>(sQKp)[tid + 256] = qkp4[tid + 256];
        if (tid < 128)
            reinterpret_cast<float4*>(sOm)[tid] =
                reinterpret_cast<const float4*>(omega + ((size_t)(b * L_ + ibase)) * L_)[tid];
        if (tid < 32)
            reinterpret_cast<float4*>(st)[tid] =
                reinterpret_cast<const float4*>(t + (size_t)b * L_)[tid];
        if (tid < R_) sS[tid] = s[tid];
    }
    __syncthreads();

    // combine the two half-head dots; Phi/Psi for 4 i's x 128 j's
    if (tid < 128) sQKh[tid] = sQKp[tid * 16 + 2 * h] + sQKp[tid * 16 + 2 * h + 1];
    #pragma unroll
    for (int p = 0; p < 2; ++p) {
        const int idx = tid + p * 256;
        const int wi = idx >> 7, j = idx & 127;
        const float dtv = fabsf(st[ibase + wi] - st[j]);
        float Phi = 0.f, Psi = 0.f;
        #pragma unroll
        for (int r = 0; r < R_; ++r) {
            const float e = expf(-dtv * sS[r]);
            Phi += e;
            Psi += e * e;
        }
        sPhi[idx] = Phi;
        sPsi[idx] = Psi;
    }
    __syncthreads();

    // softmax: wave w -> i = ibase+w (lanes cover j and j+64)
    const int w = tid >> 6, lane = tid & 63;
    const int i = ibase + w;
    {
        const float invtemp = 0.17677669529663687f;  // 1/sqrt(32)
        const int j0 = lane, j1 = lane + 64;
        float l0 = (j0 <= i) ? sOm[w*L_ + j0] * sPsi[w*L_ + j0] * sQKh[j0] * invtemp : -3.0e38f;
        float l1 = (j1 <= i) ? sOm[w*L_ + j1] * sPsi[w*L_ + j1] * sQKh[j1] * invtemp : -3.0e38f;
        const float mx = wredmax64(fmaxf(l0, l1));
        const float e0 = (j0 <= i) ? expf(l0 - mx) : 0.f;
        const float e1 = (j1 <= i) ? expf(l1 - mx) : 0.f;
        const float inv = 1.0f / wredsum64(e0 + e1);
        const float a0 = e0 * inv, a1 = e1 * inv;
        sAttn[w*L_ + j0] = a0;
        sAttn[w*L_ + j1] = a1;
        const size_t ab = (size_t)BL_ * D_ + (((size_t)(b * H_ + h) * L_ + i) * L_);
        dout[ab + j0] = a0;
        dout[ab + j1] = a1;
    }
    __syncthreads();

    // mid for 4 i's: each pv float4 load feeds 4 accumulators
    {
        const int jg = tid >> 3, c4 = tid & 7;
        const int gc4 = h * 8 + c4;
        const float4* pv4 = reinterpret_cast<const float4*>(pv + (size_t)b * L_ * D_);
        float4 acc[4];
        #pragma unroll
        for (int ww = 0; ww < 4; ++ww) acc[ww] = make_float4(0, 0, 0, 0);
        #pragma unroll
        for (int jj = 0; jj < 4; ++jj) {
            const int j = jg + jj * 32;
            const float4 p = pv4[j * 64 + gc4];
            #pragma unroll
            for (int ww = 0; ww < 4; ++ww) {
                const float wgt = sAttn[ww*L_ + j] * sPhi[ww*L_ + j];  // 0 beyond causal
                acc[ww].x += wgt * p.x; acc[ww].y += wgt * p.y;
                acc[ww].z += wgt * p.z; acc[ww].w += wgt * p.w;
            }
        }
        #pragma unroll
        for (int ww = 0; ww < 4; ++ww)
            *reinterpret_cast<float4*>(&partF[(jg * 32 + ww * 8 + c4) * 4]) = acc[ww];
    }
    __syncthreads();
    if (tid < 128) {   // reduce over jg: float idx jg*128 + w*32 + cc
        const int ww = tid >> 5, cc = tid & 31;
        float sum = 0.f;
        #pragma unroll
        for (int g = 0; g < 32; ++g) sum += partF[g * 128 + ww * 32 + cc];
        sMid[ww][cc] = sum;
    }
    __syncthreads();

    // fc fold-in: wave w handles row i = ibase+w; lane covers float4 col `lane`.
    // Each wave reads the SAME 32 fc_w rows (head h's k-slice) — 1KB coalesced
    // lines, L1/L2 resident across the 64 blocks sharing this head. sMid reads
    // are same-address broadcasts (conflict-free). 4 atomics/thread, no
    // intra-block collisions; 8 heads collide per out element across blocks.
    {
        const float4* fw4 = reinterpret_cast<const float4*>(fc_w);
        float4 a = {0, 0, 0, 0};
        #pragma unroll
        for (int cc = 0; cc < 32; ++cc) {
            const float x = sMid[w][cc];
            const float4 wv = fw4[(h * 32 + cc) * 64 + lane];
            a.x += x * wv.x; a.y += x * wv.y; a.z += x * wv.z; a.w += x * wv.w;
        }
        float* op = dout + (size_t)(b * L_ + i) * D_ + lane * 4;
        atomicAdd(op + 0, a.x);
        atomicAdd(op + 1, a.y);
        atomicAdd(op + 2, a.z);
        atomicAdd(op + 3, a.w);
    }
}

extern "C" void kernel_launch(void* const* d_in, const int* in_sizes, int n_in,
                              void* d_out, int out_size, void* d_ws, size_t ws_size,
                              hipStream_t stream) {
    const float* q     = (const float*)d_in[0];
    const float* k     = (const float*)d_in[1];
    const float* v     = (const float*)d_in[2];
    const float* t     = (const float*)d_in[3];
    const float* omega = (const float*)d_in[4];
    // d_in[5] = mask (bool) — causal triu(1), hardcoded as j<=i, not read
    const float* Wq    = (const float*)d_in[6];
    const float* Wk    = (const float*)d_in[7];
    const float* Wv    = (const float*)d_in[8];
    const float* s     = (const float*)d_in[9];
    const float* fc_w  = (const float*)d_in[10];
    const float* fc_b  = (const float*)d_in[11];
    const float* ln_g  = (const float*)d_in[12];
    const float* ln_b  = (const float*)d_in[13];

    float* ws     = (float*)d_ws;
    float* pv     = ws;               // BL*D  = 65536 floats
    float* qkpart = ws + 65536;       // BL*16 = 4096 floats
    float* out    = (float*)d_out;    // [0,65536): out (B,L,D); [65536,327680): attn (B,H,L,L)

    hipLaunchKernelGGL(k_proj, dim3(1024), dim3(256), 0, stream,
                       q, k, v, Wq, Wk, Wv, ln_g, ln_b, fc_b, pv, qkpart, out);
    hipLaunchKernelGGL(k_attn, dim3(512), dim3(256), 0, stream,
                       t, omega, s, pv, qkpart, fc_w, out);
}

// Round 2
// 96.666 us; speedup vs baseline: 1.0405x; 1.0405x over previous
//
#include <hip/hip_runtime.h>

// Problem constants
#define B_  2
#define L_  128
#define D_  256
#define H_  8
#define R_  4
#define DK_ 32
#define BL_ (B_*L_)
#define SXP 260   // padded row stride (floats) for LDS row arrays (bank decorrelation, 16B-aligned)
#define SQH 132   // padded stride for sQKh rows (bank step 4 per head)
#define SWP 129   // padded j-stride for sW planes (head stride 516 -> 8 distinct banks)

__device__ __forceinline__ float wredsum64(float v) {
    #pragma unroll
    for (int m = 32; m >= 1; m >>= 1) v += __shfl_xor(v, m, 64);
    return v;
}
__device__ __forceinline__ float wredmax64(float v) {
    #pragma unroll
    for (int m = 32; m >= 1; m >>= 1) v = fmaxf(v, __shfl_xor(v, m, 64));
    return v;
}

// K1: grid 1024 = 64 rowTiles(4 rows) x 16 cg(16 cols). LN on 4 rows, then 3 GEMVs
// for 16 cols x 4 rows — each weight line serves 4 rows. qk half-head partial
// dots -> qkpart[row][16]; pv -> ws.  (identical to the round-0 kernel)
__global__ __launch_bounds__(256) void k_proj(
    const float* __restrict__ q, const float* __restrict__ k, const float* __restrict__ v,
    const float* __restrict__ Wq, const float* __restrict__ Wk, const float* __restrict__ Wv,
    const float* __restrict__ ln_g, const float* __restrict__ ln_b,
    float* __restrict__ pv, float* __restrict__ qkpart)
{
    const int blk = blockIdx.x;
    const int rowTile = blk >> 4;
    const int cg = blk & 15;                 // 16 cols per block
    const int rbase = rowTile * 4;
    const int tid = threadIdx.x;

    __shared__ __align__(16) float sx[3][4 * SXP];   // qn,k,v x 4 rows (12.5 KB)
    __shared__ __align__(16) float partF[16 * 4 * 16]; // [kg][row][col16] (4 KB)
    __shared__ float spq[4][16], spk[4][16];

    // stage q,k,v: thread -> (r = tid>>6, f4c = tid&63), loop over the 3 tensors
    {
        const int r = tid >> 6, f4c = tid & 63;
        #pragma unroll
        for (int p = 0; p < 3; ++p) {
            const float* src = (p == 0 ? q : (p == 1 ? k : v)) + (size_t)(rbase + r) * D_;
            *reinterpret_cast<float4*>(&sx[p][r * SXP + f4c * 4]) =
                reinterpret_cast<const float4*>(src)[f4c];
        }
    }
    __syncthreads();

    // LayerNorm: wave w owns row w; lane covers cols lane+64j.
    {
        const int r = tid >> 6, lane = tid & 63;
        float x0 = sx[0][r * SXP + lane];
        float x1 = sx[0][r * SXP + lane + 64];
        float x2 = sx[0][r * SXP + lane + 128];
        float x3 = sx[0][r * SXP + lane + 192];
        float s1 = x0 + x1 + x2 + x3;
        float s2 = x0*x0 + x1*x1 + x2*x2 + x3*x3;
        #pragma unroll
        for (int m = 32; m >= 1; m >>= 1) {
            s1 += __shfl_xor(s1, m, 64);
            s2 += __shfl_xor(s2, m, 64);
        }
        const float mu = s1 * (1.0f / D_);
        const float rs = rsqrtf(s2 * (1.0f / D_) - mu * mu + 1e-6f);
        sx[0][r * SXP + lane      ] = (x0 - mu) * rs * ln_g[lane      ] + ln_b[lane      ];
        sx[0][r * SXP + lane +  64] = (x1 - mu) * rs * ln_g[lane +  64] + ln_b[lane +  64];
        sx[0][r * SXP + lane + 128] = (x2 - mu) * rs * ln_g[lane + 128] + ln_b[lane + 128];
        sx[0][r * SXP + lane + 192] = (x3 - mu) * rs * ln_g[lane + 192] + ln_b[lane + 192];
    }
    __syncthreads();

    // GEMV: thread = (kg 0..15, row 0..3, c4 0..3); 16 K-steps.
    const int kg  = tid >> 4;
    const int row = (tid >> 2) & 3;
    const int c4  = tid & 3;
    const int gc4 = cg * 4 + c4;             // global float4 col (0..63)
    const int kbase = kg * 16;

    #pragma unroll
    for (int m = 0; m < 3; ++m) {
        const float4* W4 = reinterpret_cast<const float4*>(m == 0 ? Wq : (m == 1 ? Wk : Wv));
        float4 a = {0, 0, 0, 0};
        #pragma unroll
        for (int kk = 0; kk < 16; ++kk) {
            const int kr = kbase + kk;
            const float x = sx[m][row * SXP + kr];
            const float4 w = W4[kr * 64 + gc4];
            a.x += x * w.x; a.y += x * w.y; a.z += x * w.z; a.w += x * w.w;
        }
        *reinterpret_cast<float4*>(&partF[(kg * 16 + row * 4 + c4) * 4]) = a;
        __syncthreads();
        if (tid < 64) {                      // reduce over kg
            const int rr = tid >> 4, cc = tid & 15;
            float sum = 0.f;
            #pragma unroll
            for (int g = 0; g < 16; ++g) sum += partF[g * 64 + rr * 16 + cc];
            if      (m == 0) spq[rr][cc] = sum;
            else if (m == 1) spk[rr][cc] = sum;
            else             pv[(size_t)(rbase + rr) * D_ + cg * 16 + cc] = sum;
        }
        __syncthreads();
    }

    // half-head partial dot
    if (tid < 64) {
        const int rr = tid >> 4, cc = tid & 15;
        float d = spq[rr][cc] * spk[rr][cc];
        #pragma unroll
        for (int m = 8; m >= 1; m >>= 1) d += __shfl_xor(d, m, 64);
        if (cc == 0) qkpart[(size_t)(rbase + rr) * 16 + cg] = d;
    }
}

// K2: grid 64 = b x 32 iTiles; 512 threads (8 waves). One block owns 4 output
// rows COMPLETELY (all 8 heads): Phi/Psi computed ONCE (8x fewer expf than the
// per-head grid), softmax for 32 (i,h) pairs (4 per wave), PV per head slice,
// then the fc GEMV over the block's own mid rows — exclusive-ownership writes,
// NO atomics (this is what round 1 got wrong).
__global__ __launch_bounds__(512) void k_attn(
    const float* __restrict__ t, const float* __restrict__ omega, const float* __restrict__ s,
    const float* __restrict__ pv, const float* __restrict__ qkpart,
    const float* __restrict__ fc_w, const float* __restrict__ fc_b,
    const float* __restrict__ q, float* __restrict__ dout)
{
    const int blk   = blockIdx.x;
    const int b     = blk >> 5;
    const int itile = blk & 31;
    const int ibase = itile * 4;
    const int tid = threadIdx.x;
    const int w = tid >> 6, lane = tid & 63;

    __shared__ __align__(16) float sQKp[L_ * 16];      // 8 KB staged qk partials
    __shared__ __align__(16) float sQKh[H_ * SQH];     // 4.2 KB combined per head
    __shared__ __align__(16) float sOm[4 * L_];        // 2 KB
    __shared__ __align__(16) float sPhi[4 * L_], sPsi[4 * L_];
    __shared__ __align__(16) float sW[H_ * 4 * SWP];   // 16.5 KB attn*phi weights
    __shared__ __align__(16) float partF[8 * 4 * 64 * 4]; // 32 KB (PV partials, reused for fc)
    __shared__ __align__(16) float sMid[4 * SXP];      // 4.2 KB
    __shared__ float st[L_], sS[R_];

    // ---- staging ----
    {
        const float4* qkp4 = reinterpret_cast<const float4*>(qkpart + (size_t)b * L_ * 16);
        reinterpret_cast<float4*>(sQKp)[tid] = qkp4[tid];          // 512 float4 exactly
        if (tid < 128)
            reinterpret_cast<float4*>(sOm)[tid] =
                reinterpret_cast<const float4*>(omega + ((size_t)(b * L_ + ibase)) * L_)[tid];
        if (tid < 32)
            reinterpret_cast<float4*>(st)[tid] =
                reinterpret_cast<const float4*>(t + (size_t)b * L_)[tid];
        if (tid < R_) sS[tid] = s[tid];
    }
    __syncthreads();

    // ---- Phi/Psi once for all heads: 512 (i_local,j) entries, 1 per thread ----
    {
        const int wi = tid >> 7, j = tid & 127;
        const float dtv = fabsf(st[ibase + wi] - st[j]);
        float Phi = 0.f, Psi = 0.f;
        #pragma unroll
        for (int r = 0; r < R_; ++r) {
            const float e = expf(-dtv * sS[r]);
            Phi += e;
            Psi += e * e;
        }
        sPhi[wi * L_ + j] = Phi;
        sPsi[wi * L_ + j] = Psi;
    }
    // ---- combine half-head dots -> sQKh[h][j] (head-major, conflict-free reads) ----
    #pragma unroll
    for (int p = 0; p < 2; ++p) {
        const int idx = tid + p * 512;
        const int j = idx >> 3, h = idx & 7;
        sQKh[h * SQH + j] = sQKp[j * 16 + 2 * h] + sQKp[j * 16 + 2 * h + 1];
    }
    __syncthreads();

    // ---- softmax: wave w -> (i_local = w>>1, heads (w&1)*4 .. +3) ----
    {
        const int il = w >> 1;
        const int i  = ibase + il;
        const int hb = (w & 1) * 4;
        const float invtemp = 0.17677669529663687f;  // 1/sqrt(32)
        const int j0 = lane, j1 = lane + 64;
        const float c0 = sOm[il*L_ + j0] * sPsi[il*L_ + j0] * invtemp;
        const float c1 = sOm[il*L_ + j1] * sPsi[il*L_ + j1] * invtemp;
        const float ph0 = sPhi[il*L_ + j0], ph1 = sPhi[il*L_ + j1];
        #pragma unroll
        for (int hh = 0; hh < 4; ++hh) {
            const int h = hb + hh;
            float l0 = (j0 <= i) ? c0 * sQKh[h * SQH + j0] : -3.0e38f;
            float l1 = (j1 <= i) ? c1 * sQKh[h * SQH + j1] : -3.0e38f;
            const float mx = wredmax64(fmaxf(l0, l1));
            const float e0 = (j0 <= i) ? expf(l0 - mx) : 0.f;
            const float e1 = (j1 <= i) ? expf(l1 - mx) : 0.f;
            const float inv = 1.0f / wredsum64(e0 + e1);
            const float a0 = e0 * inv, a1 = e1 * inv;
            const size_t ab = (size_t)BL_ * D_ + (((size_t)(b * H_ + h) * L_ + i) * L_);
            dout[ab + j0] = a0;
            dout[ab + j1] = a1;
            sW[(h * 4 + il) * SWP + j0] = a0 * ph0;   // 0 beyond causal
            sW[(h * 4 + il) * SWP + j1] = a1 * ph1;
        }
    }
    __syncthreads();

    // ---- PV: thread (jg = w, c = lane); head h = c>>3; 16 j's per thread ----
    {
        const int c = lane, jg = w;
        const int h = c >> 3;
        const float4* pv4 = reinterpret_cast<const float4*>(pv + (size_t)b * L_ * D_);
        float4 acc[4];
        #pragma unroll
        for (int il = 0; il < 4; ++il) acc[il] = make_float4(0, 0, 0, 0);
        #pragma unroll
        for (int jj = 0; jj < 16; ++jj) {
            const int j = jg * 16 + jj;
            const float4 p = pv4[j * 64 + c];
            #pragma unroll
            for (int il = 0; il < 4; ++il) {
                const float wgt = sW[(h * 4 + il) * SWP + j];  // 8 banks, broadcast per 8 lanes
                acc[il].x += wgt * p.x; acc[il].y += wgt * p.y;
                acc[il].z += wgt * p.z; acc[il].w += wgt * p.w;
            }
        }
        #pragma unroll
        for (int il = 0; il < 4; ++il)
            *reinterpret_cast<float4*>(&partF[((jg * 4 + il) * 64 + c) * 4]) = acc[il];
    }
    __syncthreads();
    if (tid < 256) {   // reduce over jg -> sMid[4][256]
        const int il = tid >> 6, c = tid & 63;
        float4 sum = make_float4(0, 0, 0, 0);
        #pragma unroll
        for (int g = 0; g < 8; ++g) {
            const float4 p = *reinterpret_cast<float4*>(&partF[((g * 4 + il) * 64 + c) * 4]);
            sum.x += p.x; sum.y += p.y; sum.z += p.z; sum.w += p.w;
        }
        *reinterpret_cast<float4*>(&sMid[il * SXP + c * 4]) = sum;
    }
    __syncthreads();

    // ---- fc: thread (kseg = w, c4 = lane); each wave owns 32 k's (no duplicate
    // fc_w traffic across waves); partials for all 4 rows ----
    {
        const int kseg = w, c4 = lane;
        const float4* fw4 = reinterpret_cast<const float4*>(fc_w);
        float4 acc[4];
        #pragma unroll
        for (int r = 0; r < 4; ++r) acc[r] = make_float4(0, 0, 0, 0);
        #pragma unroll
        for (int kk = 0; kk < 32; ++kk) {
            const int k = kseg * 32 + kk;
            const float4 wv = fw4[k * 64 + c4];
            #pragma unroll
            for (int r = 0; r < 4; ++r) {
                const float x = sMid[r * SXP + k];   // LDS broadcast
                acc[r].x += x * wv.x; acc[r].y += x * wv.y;
                acc[r].z += x * wv.z; acc[r].w += x * wv.w;
            }
        }
        #pragma unroll
        for (int r = 0; r < 4; ++r)
            *reinterpret_cast<float4*>(&partF[((kseg * 4 + r) * 64 + c4) * 4]) = acc[r];
    }
    __syncthreads();
    if (tid < 256) {   // reduce over kseg + bias + residual -> out (exclusive rows)
        const int r = tid >> 6, c4 = tid & 63;
        const float4 bb = reinterpret_cast<const float4*>(fc_b)[c4];
        const float4 res = reinterpret_cast<const float4*>(q)[((size_t)(b * L_ + ibase + r)) * 64 + c4];
        float4 sum = make_float4(bb.x + res.x, bb.y + res.y, bb.z + res.z, bb.w + res.w);
        #pragma unroll
        for (int g = 0; g < 8; ++g) {
            const float4 p = *reinterpret_cast<float4*>(&partF[((g * 4 + r) * 64 + c4) * 4]);
            sum.x += p.x; sum.y += p.y; sum.z += p.z; sum.w += p.w;
        }
        reinterpret_cast<float4*>(dout)[((size_t)(b * L_ + ibase + r)) * 64 + c4] = sum;
    }
}

extern "C" void kernel_launch(void* const* d_in, const int* in_sizes, int n_in,
                              void* d_out, int out_size, void* d_ws, size_t ws_size,
                              hipStream_t stream) {
    const float* q     = (const float*)d_in[0];
    const float* k     = (const float*)d_in[1];
    const float* v     = (const float*)d_in[2];
    const float* t     = (const float*)d_in[3];
    const float* omega = (const float*)d_in[4];
    // d_in[5] = mask (bool) — causal triu(1), hardcoded as j<=i, not read
    const float* Wq    = (const float*)d_in[6];
    const float* Wk    = (const float*)d_in[7];
    const float* Wv    = (const float*)d_in[8];
    const float* s     = (const float*)d_in[9];
    const float* fc_w  = (const float*)d_in[10];
    const float* fc_b  = (const float*)d_in[11];
    const float* ln_g  = (const float*)d_in[12];
    const float* ln_b  = (const float*)d_in[13];

    float* ws     = (float*)d_ws;
    float* pv     = ws;               // BL*D  = 65536 floats
    float* qkpart = ws + 65536;       // BL*16 = 4096 floats
    float* out    = (float*)d_out;    // [0,65536): out (B,L,D); [65536,327680): attn (B,H,L,L)

    hipLaunchKernelGGL(k_proj, dim3(1024), dim3(256), 0, stream,
                       q, k, v, Wq, Wk, Wv, ln_g, ln_b, pv, qkpart);
    hipLaunchKernelGGL(k_attn, dim3(64), dim3(512), 0, stream,
                       t, omega, s, pv, qkpart, fc_w, fc_b, q, out);
}